// Round 12
// baseline (176.348 us; speedup 1.0000x reference)
//
#include <hip/hip_runtime.h>
#include <hip/hip_bf16.h>
#include <stdint.h>

// Router GEMM: out[8192,768] (fp32) = X[8192,6144] @ W[768,6144]^T
// Device buffers hold FP32 upcasts of the bf16 data (round-6 discovery).
// Round 12: clean 2-deep prefetch test (r9 retried WITHOUT spill):
//   - wave-tile 64x32 (acc=32), 512 thr / 8 waves -> regs ~108, no spill
//   - two pr banks, statically indexed 2x-unrolled loop (rule #20)
//   - issue-to-write distance ~1.7 steps (~500-1000 cyc) covers HBM latency
//   - single LDS buffer + 2 barriers (r8-proven sync), SK=4 (3 clean batches
//     of 2 blocks/CU), XCD-local X panels, r9-verified swizzle, atomics

#define M_DIM 8192
#define N_DIM 768
#define K_DIM 6144

#define BM 128
#define BN 128
#define BK 32
#define SPLITK 4
#define KSEG (K_DIM / SPLITK)    // 1536 per block
#define NT (KSEG / BK)           // 48 K-steps (even)

typedef __bf16 bf16x8 __attribute__((ext_vector_type(8)));
typedef float f32x4 __attribute__((ext_vector_type(4)));

static __device__ __forceinline__ __bf16 bf16_trunc(float f) {
    uint32_t u = __builtin_bit_cast(uint32_t, f);
    return __builtin_bit_cast(__bf16, (uint16_t)(u >> 16));  // exact on upcast data
}

static __device__ __forceinline__ bf16x8 pack_bf16x8(f32x4 a, f32x4 b) {
    bf16x8 r;
    #pragma unroll
    for (int j = 0; j < 4; ++j) {
        r[j]     = bf16_trunc(a[j]);
        r[4 + j] = bf16_trunc(b[j]);
    }
    return r;
}

__global__ __launch_bounds__(512, 2) void router_gemm_pf2_kernel(
    const float* __restrict__ X, const float* __restrict__ W,
    float* __restrict__ out)
{
    __shared__ __align__(16) __bf16 As[BM * BK];   // 8 KiB
    __shared__ __align__(16) __bf16 Bs[BN * BK];   // 8 KiB

    const int tid  = threadIdx.x;
    const int w    = tid >> 6;             // wave 0..7
    const int lane = tid & 63;

    // XCD decode: XCD x owns {bmi 0..7} x {bn 0..5} x {ks 0..3};
    // bm = x*8+bmi -> each X panel is XCD-local.
    const int xcd  = blockIdx.x & 7;
    const int slot = blockIdx.x >> 3;      // 0..191
    const int bmi  = slot & 7;
    const int tt   = slot >> 3;            // 0..23
    const int bn   = tt % 6;
    const int ks   = tt / 6;               // 0..3
    const int bm   = xcd * 8 + bmi;        // 0..63

    const int kbase = ks * KSEG;

    const int wr = w >> 2;                 // wave row 0..1 (64 m-rows)
    const int wc = w & 3;                  // wave col 0..3 (32 n-cols)

    const int lrow = lane & 15;
    const int kg   = lane >> 4;

    // staging: 512 threads, each moves one A-unit + one B-unit (8 elems each).
    // unit tid: row = tid>>2 (0..127), k8 = tid&3.
    const int srow = tid >> 2;
    const int sk8  = tid & 3;
    // conflict-free swizzle (r9-verified, counter=0): slot = k8 ^ ((row>>1)&3)
    const int wslot0 = (sk8 ^ ((srow >> 1) & 3)) * 8;

    const float* Xg = X + (size_t)(bm * BM) * K_DIM;
    const float* Wg = W + (size_t)(bn * BN) * K_DIM;
    const float* xrow = Xg + (size_t)srow * K_DIM + sk8 * 8;
    const float* wrow = Wg + (size_t)srow * K_DIM + sk8 * 8;

    f32x4 pr0[4], pr1[4];   // two static banks (rule #20: no runtime indexing)

    #define ISSUE_LOADS(P, K0)                        \
        do {                                          \
            P[0] = *(const f32x4*)(xrow + (K0));      \
            P[1] = *(const f32x4*)(xrow + (K0) + 4);  \
            P[2] = *(const f32x4*)(wrow + (K0));      \
            P[3] = *(const f32x4*)(wrow + (K0) + 4);  \
        } while (0)

    #define WRITE_LDS(P)                                                      \
        do {                                                                  \
            *(bf16x8*)(As + srow * BK + wslot0) = pack_bf16x8(P[0], P[1]);    \
            *(bf16x8*)(Bs + srow * BK + wslot0) = pack_bf16x8(P[2], P[3]);    \
        } while (0)

    f32x4 acc[4][2] = {};

    const int rslot = (kg ^ ((lrow >> 1) & 3)) * 8;
    const int arow0 = wr * 64 + lrow;      // + mf*16
    const int brow0 = wc * 32 + lrow;      // + nf*16

    #define COMPUTE()                                                         \
        do {                                                                  \
            bf16x8 a[4], b[2];                                                \
            _Pragma("unroll")                                                 \
            for (int mf = 0; mf < 4; ++mf)                                    \
                a[mf] = *(const bf16x8*)(As + (arow0 + mf * 16) * BK + rslot);\
            _Pragma("unroll")                                                 \
            for (int nf = 0; nf < 2; ++nf)                                    \
                b[nf] = *(const bf16x8*)(Bs + (brow0 + nf * 16) * BK + rslot);\
            _Pragma("unroll")                                                 \
            for (int mf = 0; mf < 4; ++mf)                                    \
                _Pragma("unroll")                                             \
                for (int nf = 0; nf < 2; ++nf)                                \
                    acc[mf][nf] = __builtin_amdgcn_mfma_f32_16x16x32_bf16(    \
                        a[mf], b[nf], acc[mf][nf], 0, 0, 0);                  \
        } while (0)

    // prologue: tile0 -> pr0 -> LDS; tile1 -> pr1 (in flight)
    ISSUE_LOADS(pr0, kbase);
    ISSUE_LOADS(pr1, kbase + BK);
    WRITE_LDS(pr0);                 // waits only pr0's 4 loads (vmcnt counted)
    __syncthreads();

    for (int t = 0; t < NT; t += 2) {
        // even sub-step: compute tile t; stage t+1 (pr1); refill pr0 <- t+2
        if (t + 2 < NT) ISSUE_LOADS(pr0, kbase + (t + 2) * BK);
        COMPUTE();
        __syncthreads();                    // frag reads done
        if (t + 1 < NT) WRITE_LDS(pr1);     // pr1 issued ~1.7 steps ago
        __syncthreads();                    // staging visible
        // odd sub-step: compute tile t+1; stage t+2 (pr0); refill pr1 <- t+3
        if (t + 3 < NT) ISSUE_LOADS(pr1, kbase + (t + 3) * BK);
        COMPUTE();
        __syncthreads();
        if (t + 2 < NT) WRITE_LDS(pr0);
        __syncthreads();
    }

    // epilogue: relaxed device-scope fp32 atomic add (out zeroed in launch).
    // C/D layout col = lane&15, row = (lane>>4)*4 + reg (verified).
    const int orow0 = bm * BM + wr * 64 + kg * 4;
    const int ocol0 = bn * BN + wc * 32 + lrow;
    #pragma unroll
    for (int mf = 0; mf < 4; ++mf)
        #pragma unroll
        for (int nf = 0; nf < 2; ++nf)
            #pragma unroll
            for (int r = 0; r < 4; ++r) {
                float* o = out + (size_t)(orow0 + mf * 16 + r) * N_DIM
                               + (ocol0 + nf * 16);
                __hip_atomic_fetch_add(o, acc[mf][nf][r],
                                       __ATOMIC_RELAXED, __HIP_MEMORY_SCOPE_AGENT);
            }

    #undef ISSUE_LOADS
    #undef WRITE_LDS
    #undef COMPUTE
}

extern "C" void kernel_launch(void* const* d_in, const int* in_sizes, int n_in,
                              void* d_out, int out_size, void* d_ws, size_t ws_size,
                              hipStream_t stream) {
    const float* X;
    const float* W;
    if (in_sizes[0] == M_DIM * K_DIM) {
        X = (const float*)d_in[0];
        W = (const float*)d_in[1];
    } else {
        X = (const float*)d_in[1];
        W = (const float*)d_in[0];
    }
    float* out = (float*)d_out;

    // zero-init for atomic accumulation (async stream op: graph-capture-safe)
    hipMemsetAsync(out, 0, (size_t)M_DIM * N_DIM * sizeof(float), stream);

    const int grid = (M_DIM / BM) * (N_DIM / BN) * SPLITK;   // 64*6*4 = 1536
    hipLaunchKernelGGL(router_gemm_pf2_kernel, dim3(grid), dim3(512), 0, stream,
                       X, W, out);
}